// Round 1
// baseline (52.871 us; speedup 1.0000x reference)
//
#include <hip/hip_runtime.h>
#include <cmath>

#define V 50257
#define H 1024

// ws layout (floats):
// [0, 4096)          gates
// [4096, 5120)       h1
// [5120]             s_total (m + log sum)
// [5128, 5128+2*NB)  per-block (max, sumexp) partials for logits
#define WS_GATES 0
#define WS_H1 4096
#define WS_STOT 5120
#define WS_PART 5128

__device__ __forceinline__ float dot4(float4 a, float4 b) {
    return a.x * b.x + a.y * b.y + a.z * b.z + a.w * b.w;
}

// gates[row] = dot(W_ih[row], relu(emb[tok])) + dot(W_hh[row], h0) + b_ih[row] + b_hh[row]
// one wave per row; 4096 rows; grid 1024 x 256
__global__ __launch_bounds__(256) void k_gates(const int* __restrict__ token,
                                               const float* __restrict__ h0,
                                               const float* __restrict__ emb,
                                               const float* __restrict__ W_ih,
                                               const float* __restrict__ W_hh,
                                               const float* __restrict__ b_ih,
                                               const float* __restrict__ b_hh,
                                               float* __restrict__ gates) {
    const int tid = threadIdx.x;
    const int wid = tid >> 6, lane = tid & 63;
    const int row = blockIdx.x * 4 + wid;
    const int tok = token[0];

    const float4* embr = (const float4*)(emb + (size_t)tok * H);
    const float4* h4   = (const float4*)h0;
    const float4* wi   = (const float4*)(W_ih + (size_t)row * H);
    const float4* wh   = (const float4*)(W_hh + (size_t)row * H);

    float acc = 0.f;
#pragma unroll
    for (int it = 0; it < 4; ++it) {
        const int k4 = it * 64 + lane;  // float4 index within the 1024-elem row
        float4 xv = embr[k4];
        xv.x = fmaxf(xv.x, 0.f); xv.y = fmaxf(xv.y, 0.f);
        xv.z = fmaxf(xv.z, 0.f); xv.w = fmaxf(xv.w, 0.f);
        float4 hv = h4[k4];
        acc += dot4(wi[k4], xv);
        acc += dot4(wh[k4], hv);
    }
#pragma unroll
    for (int off = 32; off; off >>= 1) acc += __shfl_down(acc, off);
    if (lane == 0) gates[row] = acc + b_ih[row] + b_hh[row];
}

// LSTM cell elementwise; writes h1,c1 to d_out tail and h1 to ws
__global__ __launch_bounds__(256) void k_cell(const float* __restrict__ gates,
                                              const float* __restrict__ c0,
                                              float* __restrict__ out,
                                              float* __restrict__ h1ws) {
    const int j = blockIdx.x * 256 + threadIdx.x;  // 4 blocks -> 1024
    const float gi = gates[j];
    const float gf = gates[H + j];
    const float gg = gates[2 * H + j];
    const float go = gates[3 * H + j];
    const float si = 1.f / (1.f + expf(-gi));
    const float sf = 1.f / (1.f + expf(-gf));
    const float so = 1.f / (1.f + expf(-go));
    const float c1 = sf * c0[j] + si * tanhf(gg);
    const float h1 = so * tanhf(c1);
    out[V + j]     = h1;
    out[V + H + j] = c1;
    h1ws[j]        = h1;
}

// logits[row] = dot(W_out[row], h1) + b_out[row]; 4 rows/wave, 16 rows/block.
// Also emits per-block (max, sum exp(l - max)) partials.
__global__ __launch_bounds__(256) void k_logits(const float* __restrict__ h1,
                                                const float* __restrict__ W_out,
                                                const float* __restrict__ b_out,
                                                float* __restrict__ out,
                                                float* __restrict__ partials) {
    const int tid = threadIdx.x;
    const int wid = tid >> 6, lane = tid & 63;

    float4 hv[4];
    const float4* h4 = (const float4*)h1;
#pragma unroll
    for (int it = 0; it < 4; ++it) hv[it] = h4[it * 64 + lane];

    const int row0 = (blockIdx.x * 4 + wid) * 4;
    float vals[4];
#pragma unroll
    for (int r = 0; r < 4; ++r) {
        const int row = row0 + r;
        float acc = 0.f;
        if (row < V) {
            const float4* w = (const float4*)(W_out + (size_t)row * H);
#pragma unroll
            for (int it = 0; it < 4; ++it) acc += dot4(w[it * 64 + lane], hv[it]);
        }
#pragma unroll
        for (int off = 32; off; off >>= 1) acc += __shfl_down(acc, off);
        vals[r] = acc;  // valid at lane 0
    }

    __shared__ float blk[16];
    if (lane == 0) {
#pragma unroll
        for (int r = 0; r < 4; ++r) {
            const int row = row0 + r;
            if (row < V) {
                const float l = vals[r] + b_out[row];
                out[row] = l;
                blk[wid * 4 + r] = l;
            } else {
                blk[wid * 4 + r] = -INFINITY;
            }
        }
    }
    __syncthreads();
    if (tid == 0) {
        float m = -INFINITY;
        for (int i = 0; i < 16; ++i) m = fmaxf(m, blk[i]);
        float s = 0.f;
        for (int i = 0; i < 16; ++i) s += expf(blk[i] - m);
        partials[2 * blockIdx.x]     = m;
        partials[2 * blockIdx.x + 1] = s;
    }
}

// single block: merge partials -> s_total = m + log(sum)
__global__ __launch_bounds__(256) void k_combine(const float* __restrict__ partials,
                                                 int n, float* __restrict__ s_total) {
    const int tid = threadIdx.x;
    float m = -INFINITY, s = 0.f;
    for (int i = tid; i < n; i += 256) {
        const float mi = partials[2 * i], si = partials[2 * i + 1];
        const float mn = fmaxf(m, mi);
        s = s * expf(m - mn) + si * expf(mi - mn);
        m = mn;
    }
#pragma unroll
    for (int off = 32; off; off >>= 1) {
        const float mo = __shfl_down(m, off), so = __shfl_down(s, off);
        const float mn = fmaxf(m, mo);
        s = s * expf(m - mn) + so * expf(mo - mn);
        m = mn;
    }
    __shared__ float sm[4], ss[4];
    const int wid = tid >> 6, lane = tid & 63;
    if (lane == 0) { sm[wid] = m; ss[wid] = s; }
    __syncthreads();
    if (tid == 0) {
        float M = sm[0], S = ss[0];
        for (int w = 1; w < 4; ++w) {
            const float mn = fmaxf(M, sm[w]);
            S = S * expf(M - mn) + ss[w] * expf(sm[w] - mn);
            M = mn;
        }
        *s_total = M + logf(S);
    }
}

__global__ __launch_bounds__(256) void k_sub(float* __restrict__ out,
                                             const float* __restrict__ s_total) {
    const int i = blockIdx.x * 256 + threadIdx.x;
    if (i < V) out[i] -= *s_total;
}

extern "C" void kernel_launch(void* const* d_in, const int* in_sizes, int n_in,
                              void* d_out, int out_size, void* d_ws, size_t ws_size,
                              hipStream_t stream) {
    const int*   token = (const int*)d_in[0];
    const float* h0    = (const float*)d_in[1];
    const float* c0    = (const float*)d_in[2];
    const float* emb   = (const float*)d_in[3];
    const float* W_ih  = (const float*)d_in[4];
    const float* W_hh  = (const float*)d_in[5];
    const float* b_ih  = (const float*)d_in[6];
    const float* b_hh  = (const float*)d_in[7];
    const float* W_out = (const float*)d_in[8];
    const float* b_out = (const float*)d_in[9];

    float* out = (float*)d_out;
    float* ws  = (float*)d_ws;
    float* gates    = ws + WS_GATES;
    float* h1ws     = ws + WS_H1;
    float* s_total  = ws + WS_STOT;
    float* partials = ws + WS_PART;

    const int nblk_logits = (V + 15) / 16;  // 3142

    k_gates<<<1024, 256, 0, stream>>>(token, h0, emb, W_ih, W_hh, b_ih, b_hh, gates);
    k_cell<<<4, 256, 0, stream>>>(gates, c0, out, h1ws);
    k_logits<<<nblk_logits, 256, 0, stream>>>(h1ws, W_out, b_out, out, partials);
    k_combine<<<1, 256, 0, stream>>>(partials, nblk_logits, s_total);
    k_sub<<<(V + 255) / 256, 256, 0, stream>>>(out, s_total);
}